// Round 1
// baseline (438.315 us; speedup 1.0000x reference)
//
#include <hip/hip_runtime.h>
#include <hip/hip_bf16.h>
#include <math.h>

#define BB 4
#define SS 512
#define FF 512
#define HH 8
#define DD 64
#define RR 64
#define OO 512
#define HDIM 512

// workspace layout (float offsets)
#define OFF_Q     0u
#define OFF_K     1048576u
#define OFF_V     2097152u
#define OFF_QE    3145728u
#define OFF_W     4194304u
#define OFF_CTX   5242880u
#define OFF_FLAGS 6291456u

__device__ __forceinline__ int load_adj_v(const int* __restrict__ adj, long idx, int is64) {
    return is64 ? adj[2 * idx] : adj[idx];
}
__device__ __forceinline__ int load_mask_v(const void* __restrict__ mask, int idx, int isbyte) {
    return isbyte ? (int)((const unsigned char*)mask)[idx] : ((const int*)mask)[idx];
}

// ---------------------------------------------------------------------------
// Detect whether adj arrived as int64 (odd words all zero) and whether mask
// arrived byte-packed (words > 1 appear). Flags recomputed every call (ws is
// re-poisoned by the harness).
// ---------------------------------------------------------------------------
__global__ __launch_bounds__(256) void k_detect(const int* __restrict__ adj,
                                                const unsigned int* __restrict__ mask,
                                                int* __restrict__ flags)
{
    __shared__ int s_odd, s_big;
    if (threadIdx.x == 0) { s_odd = 0; s_big = 0; }
    __syncthreads();
    int odd = 0, big = 0;
    for (int i = threadIdx.x; i < 512; i += 256) {
        if (adj[2 * i + 1] != 0) odd = 1;   // int32 adj: random 0..63 here
        if (mask[i] > 1u) big = 1;          // byte-packed mask: 0x01010101 words
    }
    if (odd) atomicOr(&s_odd, 1);
    if (big) atomicOr(&s_big, 1);
    __syncthreads();
    if (threadIdx.x == 0) {
        flags[0] = s_odd ? 0 : 1;   // 1 -> adj is int64
        flags[1] = s_big ? 1 : 0;   // 1 -> mask is bytes
    }
}

// ---------------------------------------------------------------------------
// QKV projections: A(2048x512) @ W(512x512) + b -> (B,H,S,D). grid.z picks q/k/v.
// 64x64 tile, BK=32, 4x4 micro-tile. As padded to 33 (write conflict-free,
// read 2-way = free). Bs reads via float4 broadcast.
// ---------------------------------------------------------------------------
__global__ __launch_bounds__(256) void k_proj(
    const float* __restrict__ query, const float* __restrict__ key, const float* __restrict__ value,
    const float* __restrict__ Wq, const float* __restrict__ bq,
    const float* __restrict__ Wk, const float* __restrict__ bk,
    const float* __restrict__ Wv, const float* __restrict__ bv,
    float* __restrict__ ws)
{
    const int z = blockIdx.z;
    const float* A    = (z == 0) ? query : (z == 1) ? key : value;
    const float* W    = (z == 0) ? Wq : (z == 1) ? Wk : Wv;
    const float* bias = (z == 0) ? bq : (z == 1) ? bk : bv;
    float* out = ws + ((z == 0) ? OFF_Q : (z == 1) ? OFF_K : OFF_V);

    const int n0 = blockIdx.x * 64;
    const int m0 = blockIdx.y * 64;
    __shared__ float As[64][33];
    __shared__ float Bs[32][64];
    const int tid = threadIdx.x;
    const int tm = tid & 15, tn = tid >> 4;
    float acc[4][4] = {};

    for (int k0 = 0; k0 < FF; k0 += 32) {
#pragma unroll
        for (int i = 0; i < 8; i++) {
            int idx = tid + i * 256;
            As[idx >> 5][idx & 31] = A[(size_t)(m0 + (idx >> 5)) * FF + k0 + (idx & 31)];
        }
#pragma unroll
        for (int i = 0; i < 8; i++) {
            int idx = tid + i * 256;
            Bs[idx >> 6][idx & 63] = W[(size_t)(k0 + (idx >> 6)) * HDIM + n0 + (idx & 63)];
        }
        __syncthreads();
#pragma unroll
        for (int kk = 0; kk < 32; kk++) {
            float a[4];
#pragma unroll
            for (int i = 0; i < 4; i++) a[i] = As[tm * 4 + i][kk];
            const float4 b4 = *(const float4*)&Bs[kk][tn * 4];
            const float bb[4] = {b4.x, b4.y, b4.z, b4.w};
#pragma unroll
            for (int i = 0; i < 4; i++)
#pragma unroll
                for (int j = 0; j < 4; j++)
                    acc[i][j] += a[i] * bb[j];
        }
        __syncthreads();
    }

    const int h = n0 >> 6;       // n0 is a multiple of 64
    const int d0 = tn * 4;
#pragma unroll
    for (int i = 0; i < 4; i++) {
        int m = m0 + tm * 4 + i;
        int b = m >> 9, s = m & 511;
        float4 o;
        o.x = acc[i][0] + bias[n0 + d0 + 0];
        o.y = acc[i][1] + bias[n0 + d0 + 1];
        o.z = acc[i][2] + bias[n0 + d0 + 2];
        o.w = acc[i][3] + bias[n0 + d0 + 3];
        *(float4*)&out[((size_t)(b * HH + h) * SS + s) * DD + d0] = o;
    }
}

// ---------------------------------------------------------------------------
// qe[b,h,q,r] = q[b,h,q,:] . emb_k[r,:]   (M=16384, K=64, N=64)
// ---------------------------------------------------------------------------
__global__ __launch_bounds__(256) void k_qe(const float* __restrict__ q,
                                            const float* __restrict__ emb_k,
                                            float* __restrict__ qe)
{
    __shared__ float Es[64][65];   // pad: lanes read Es[r][d] with r = lane
    __shared__ float Qs[16][64];
    const int tid = threadIdx.x;
    const int row0 = blockIdx.x * 16;
#pragma unroll
    for (int i = 0; i < 16; i++) {
        int idx = tid + i * 256;
        Es[idx >> 6][idx & 63] = emb_k[idx];
    }
#pragma unroll
    for (int i = 0; i < 4; i++) {
        int idx = tid + i * 256;
        Qs[idx >> 6][idx & 63] = q[(size_t)row0 * 64 + idx];
    }
    __syncthreads();
    const int r = tid & 63;
    const int wid = tid >> 6;
#pragma unroll
    for (int i = 0; i < 4; i++) {
        int row = wid * 4 + i;
        float acc = 0.f;
#pragma unroll
        for (int d = 0; d < 64; d++)
            acc += Qs[row][d] * Es[r][d];
        qe[(size_t)(row0 + row) * 64 + r] = acc;
    }
}

// ---------------------------------------------------------------------------
// logits[b,h,qi,c] = 0.125*(q.k + qe[b,h,qi,adj[b,qi,c]]), -inf where masked.
// 64x64 score tile per block; K-dim = D = 64, single LDS pass.
// ---------------------------------------------------------------------------
__global__ __launch_bounds__(256) void k_scores(
    const float* __restrict__ q, const float* __restrict__ kmat,
    const float* __restrict__ qe, const int* __restrict__ adj,
    const void* __restrict__ mask, const int* __restrict__ flags,
    float* __restrict__ logits)
{
    const int z = blockIdx.z;           // b*H + h
    const int b = z >> 3;
    const int q0 = blockIdx.y * 64;
    const int c0 = blockIdx.x * 64;
    __shared__ float Qs[64][65];
    __shared__ float Ks[64][65];
    __shared__ float QEs[64][65];
    const int tid = threadIdx.x;
    const int tm = tid & 15, tn = tid >> 4;

#pragma unroll
    for (int i = 0; i < 16; i++) {
        int idx = tid + i * 256;
        int rr = idx >> 6, d = idx & 63;
        Qs[rr][d]  = q   [((size_t)z * SS + q0 + rr) * DD + d];
        Ks[rr][d]  = kmat[((size_t)z * SS + c0 + rr) * DD + d];
        QEs[rr][d] = qe  [((size_t)z * SS + q0 + rr) * RR + d];
    }
    __syncthreads();

    float acc[4][4] = {};
#pragma unroll
    for (int d = 0; d < 64; d++) {
        float a[4], bb[4];
#pragma unroll
        for (int i = 0; i < 4; i++) a[i]  = Qs[tm * 4 + i][d];
#pragma unroll
        for (int j = 0; j < 4; j++) bb[j] = Ks[tn * 4 + j][d];
#pragma unroll
        for (int i = 0; i < 4; i++)
#pragma unroll
            for (int j = 0; j < 4; j++)
                acc[i][j] += a[i] * bb[j];
    }

    const int f64 = flags[0], fbyte = flags[1];
    int msk[4];
#pragma unroll
    for (int j = 0; j < 4; j++)
        msk[j] = load_mask_v(mask, b * SS + c0 + tn * 4 + j, fbyte);

#pragma unroll
    for (int i = 0; i < 4; i++) {
        const int qi = q0 + tm * 4 + i;
        const long adjrow = ((long)b * SS + qi) * SS;
        float vals[4];
#pragma unroll
        for (int j = 0; j < 4; j++) {
            int c = c0 + tn * 4 + j;
            int av = load_adj_v(adj, adjrow + c, f64);
            float val = (acc[i][j] + QEs[tm * 4 + i][av]) * 0.125f;
            vals[j] = msk[j] ? -__builtin_huge_valf() : val;
        }
        *(float4*)&logits[((size_t)z * SS + qi) * SS + c0 + tn * 4] =
            make_float4(vals[0], vals[1], vals[2], vals[3]);
    }
}

// ---------------------------------------------------------------------------
// Row softmax in place over attn (B,H,S,S). One block per row.
// ---------------------------------------------------------------------------
__global__ __launch_bounds__(256) void k_softmax(float* __restrict__ attn)
{
    float* p = attn + (size_t)blockIdx.x * SS;
    const int tid = threadIdx.x;
    const int lane = tid & 63, wid = tid >> 6;
    float v0 = p[tid], v1 = p[tid + 256];
    float m = fmaxf(v0, v1);
#pragma unroll
    for (int off = 32; off >= 1; off >>= 1)
        m = fmaxf(m, __shfl_xor(m, off, 64));
    __shared__ float rm[4], rs[4];
    if (lane == 0) rm[wid] = m;
    __syncthreads();
    m = fmaxf(fmaxf(rm[0], rm[1]), fmaxf(rm[2], rm[3]));
    float e0 = expf(v0 - m), e1 = expf(v1 - m);
    float s = e0 + e1;
#pragma unroll
    for (int off = 32; off >= 1; off >>= 1)
        s += __shfl_xor(s, off, 64);
    if (lane == 0) rs[wid] = s;
    __syncthreads();
    s = rs[0] + rs[1] + rs[2] + rs[3];
    const float inv = 1.0f / s;
    p[tid]       = e0 * inv;
    p[tid + 256] = e1 * inv;
}

// ---------------------------------------------------------------------------
// Bucket reduce: w[b,h,qi,r] = sum_k attn[b,h,qi,k] * [adj[b,qi,k]==r].
// One block per (b,qi); adj row shared across the 8 heads; LDS atomics.
// ---------------------------------------------------------------------------
__global__ __launch_bounds__(256) void k_buckets(
    const float* __restrict__ attn, const int* __restrict__ adj,
    const int* __restrict__ flags, float* __restrict__ w)
{
    const int bx = blockIdx.x;           // b*SS + qi
    const int b = bx >> 9, qi = bx & 511;
    __shared__ float w_s[8][64];
    __shared__ int adj_s[512];
    const int tid = threadIdx.x;
    const int lane = tid & 63, wid = tid >> 6;
    const int f64 = flags[0];
    for (int i = tid; i < 512; i += 256) {
        long idx = ((long)b * SS + qi) * SS + i;
        adj_s[i] = f64 ? adj[2 * idx] : adj[idx];
        w_s[i >> 6][i & 63] = 0.f;
    }
    __syncthreads();
#pragma unroll
    for (int hh = 0; hh < 2; hh++) {
        int h = wid * 2 + hh;            // each wave owns 2 heads -> low atomic contention
        const float* arow = attn + ((size_t)(b * HH + h) * SS + qi) * SS;
        for (int kk = lane; kk < 512; kk += 64)
            atomicAdd(&w_s[h][adj_s[kk]], arow[kk]);
    }
    __syncthreads();
    for (int i = tid; i < 512; i += 256) {
        int h = i >> 6, r = i & 63;
        w[((size_t)(b * HH + h) * SS + qi) * RR + r] = w_s[h][r];
    }
}

// ---------------------------------------------------------------------------
// ctx[b,s,h*64+d] = attn[b,h,s,:] @ v[b,h,:,d]  +  w[b,h,s,:] @ emb_v[:,d]
// 64(q) x 64(d) tile; 16 K-chunks of attn@v then 2 K-chunks of w@emb_v.
// ---------------------------------------------------------------------------
__global__ __launch_bounds__(256) void k_ctx(
    const float* __restrict__ attn, const float* __restrict__ v,
    const float* __restrict__ w, const float* __restrict__ emb_v,
    float* __restrict__ ctx)
{
    const int z = blockIdx.y;            // b*H + h
    const int b = z >> 3, h = z & 7;
    const int q0 = blockIdx.x * 64;
    __shared__ float As[64][33];
    __shared__ float Bs[32][64];
    const int tid = threadIdx.x;
    const int tm = tid & 15, tn = tid >> 4;
    float acc[4][4] = {};

    for (int t = 0; t < 18; t++) {
        if (t < 16) {
            const int k0 = t * 32;
#pragma unroll
            for (int i = 0; i < 8; i++) {
                int idx = tid + i * 256;
                As[idx >> 5][idx & 31] =
                    attn[((size_t)z * SS + q0 + (idx >> 5)) * SS + k0 + (idx & 31)];
            }
#pragma unroll
            for (int i = 0; i < 8; i++) {
                int idx = tid + i * 256;
                Bs[idx >> 6][idx & 63] =
                    v[((size_t)z * SS + k0 + (idx >> 6)) * DD + (idx & 63)];
            }
        } else {
            const int r0 = (t - 16) * 32;
#pragma unroll
            for (int i = 0; i < 8; i++) {
                int idx = tid + i * 256;
                As[idx >> 5][idx & 31] =
                    w[((size_t)z * SS + q0 + (idx >> 5)) * RR + r0 + (idx & 31)];
            }
#pragma unroll
            for (int i = 0; i < 8; i++) {
                int idx = tid + i * 256;
                Bs[idx >> 6][idx & 63] = emb_v[(size_t)(r0 + (idx >> 6)) * DD + (idx & 63)];
            }
        }
        __syncthreads();
#pragma unroll
        for (int kk = 0; kk < 32; kk++) {
            float a[4];
#pragma unroll
            for (int i = 0; i < 4; i++) a[i] = As[tm * 4 + i][kk];
            const float4 b4 = *(const float4*)&Bs[kk][tn * 4];
            const float bb[4] = {b4.x, b4.y, b4.z, b4.w};
#pragma unroll
            for (int i = 0; i < 4; i++)
#pragma unroll
                for (int j = 0; j < 4; j++)
                    acc[i][j] += a[i] * bb[j];
        }
        __syncthreads();
    }

#pragma unroll
    for (int i = 0; i < 4; i++) {
        int s = q0 + tm * 4 + i;
        float4 o = make_float4(acc[i][0], acc[i][1], acc[i][2], acc[i][3]);
        *(float4*)&ctx[((size_t)b * SS + s) * HDIM + h * DD + tn * 4] = o;
    }
}

// ---------------------------------------------------------------------------
// out = ctx(2048x512) @ Wo(512x512) + bo
// ---------------------------------------------------------------------------
__global__ __launch_bounds__(256) void k_out(
    const float* __restrict__ ctx, const float* __restrict__ Wo,
    const float* __restrict__ bo, float* __restrict__ out)
{
    const int n0 = blockIdx.x * 64;
    const int m0 = blockIdx.y * 64;
    __shared__ float As[64][33];
    __shared__ float Bs[32][64];
    const int tid = threadIdx.x;
    const int tm = tid & 15, tn = tid >> 4;
    float acc[4][4] = {};

    for (int k0 = 0; k0 < HDIM; k0 += 32) {
#pragma unroll
        for (int i = 0; i < 8; i++) {
            int idx = tid + i * 256;
            As[idx >> 5][idx & 31] = ctx[(size_t)(m0 + (idx >> 5)) * HDIM + k0 + (idx & 31)];
        }
#pragma unroll
        for (int i = 0; i < 8; i++) {
            int idx = tid + i * 256;
            Bs[idx >> 6][idx & 63] = Wo[(size_t)(k0 + (idx >> 6)) * OO + n0 + (idx & 63)];
        }
        __syncthreads();
#pragma unroll
        for (int kk = 0; kk < 32; kk++) {
            float a[4];
#pragma unroll
            for (int i = 0; i < 4; i++) a[i] = As[tm * 4 + i][kk];
            const float4 b4 = *(const float4*)&Bs[kk][tn * 4];
            const float bb[4] = {b4.x, b4.y, b4.z, b4.w};
#pragma unroll
            for (int i = 0; i < 4; i++)
#pragma unroll
                for (int j = 0; j < 4; j++)
                    acc[i][j] += a[i] * bb[j];
        }
        __syncthreads();
    }

#pragma unroll
    for (int i = 0; i < 4; i++) {
        int m = m0 + tm * 4 + i;
        float4 o;
        o.x = acc[i][0] + bo[n0 + tn * 4 + 0];
        o.y = acc[i][1] + bo[n0 + tn * 4 + 1];
        o.z = acc[i][2] + bo[n0 + tn * 4 + 2];
        o.w = acc[i][3] + bo[n0 + tn * 4 + 3];
        *(float4*)&out[(size_t)m * OO + n0 + tn * 4] = o;
    }
}

extern "C" void kernel_launch(void* const* d_in, const int* in_sizes, int n_in,
                              void* d_out, int out_size, void* d_ws, size_t ws_size,
                              hipStream_t stream)
{
    const float* key   = (const float*)d_in[0];
    const float* value = (const float*)d_in[1];
    const float* query = (const float*)d_in[2];
    const void*  mask  = d_in[3];
    const int*   adj   = (const int*)d_in[4];
    const float* Wq    = (const float*)d_in[5];
    const float* bq    = (const float*)d_in[6];
    const float* Wk    = (const float*)d_in[7];
    const float* bk    = (const float*)d_in[8];
    const float* Wv    = (const float*)d_in[9];
    const float* bv    = (const float*)d_in[10];
    const float* Wo    = (const float*)d_in[11];
    const float* bo    = (const float*)d_in[12];
    const float* emb_k = (const float*)d_in[13];
    const float* emb_v = (const float*)d_in[14];

    float* ws   = (float*)d_ws;
    float* outp = (float*)d_out;                       // (B,S,OUT)
    float* attn = outp + (size_t)BB * SS * OO;         // (B,H,S,S)
    int*  flags = (int*)(ws + OFF_FLAGS);

    k_detect <<<1, 256, 0, stream>>>(adj, (const unsigned int*)mask, flags);
    k_proj   <<<dim3(8, 32, 3), 256, 0, stream>>>(query, key, value,
                                                  Wq, bq, Wk, bk, Wv, bv, ws);
    k_qe     <<<1024, 256, 0, stream>>>(ws + OFF_Q, emb_k, ws + OFF_QE);
    k_scores <<<dim3(8, 8, 32), 256, 0, stream>>>(ws + OFF_Q, ws + OFF_K, ws + OFF_QE,
                                                  adj, mask, flags, attn);
    k_softmax<<<16384, 256, 0, stream>>>(attn);
    k_buckets<<<2048, 256, 0, stream>>>(attn, adj, flags, ws + OFF_W);
    k_ctx    <<<dim3(8, 32), 256, 0, stream>>>(attn, ws + OFF_V, ws + OFF_W, emb_v,
                                               ws + OFF_CTX);
    k_out    <<<dim3(8, 32), 256, 0, stream>>>(ws + OFF_CTX, Wo, bo, outp);
}

// Round 2
// 286.123 us; speedup vs baseline: 1.5319x; 1.5319x over previous
//
#include <hip/hip_runtime.h>
#include <hip/hip_bf16.h>
#include <math.h>

#define BB 4
#define SS 512
#define FF 512
#define HH 8
#define DD 64
#define RR 64
#define OO 512
#define HDIM 512

// workspace layout (float offsets)
#define OFF_Q     0u
#define OFF_K     1048576u
#define OFF_QE    2097152u
#define OFF_W     3145728u
#define OFF_CTX   4194304u
#define OFF_VT    5242880u   // bf16 (ushort) region: 32*64*512 ushorts = 524288 floats
#define OFF_FLAGS 5767168u

typedef __attribute__((ext_vector_type(4))) float f32x4;
typedef __attribute__((ext_vector_type(8))) short bf16x8;

__device__ __forceinline__ unsigned short f2bf(float f) {
    unsigned int u = __builtin_bit_cast(unsigned int, f);
    u += 0x7FFFu + ((u >> 16) & 1u);
    return (unsigned short)(u >> 16);
}
__device__ __forceinline__ int load_adj_v(const int* __restrict__ adj, long idx, int is64) {
    return is64 ? adj[2 * idx] : adj[idx];
}
__device__ __forceinline__ int load_mask_v(const void* __restrict__ mask, int idx, int isbyte) {
    return isbyte ? (int)((const unsigned char*)mask)[idx] : ((const int*)mask)[idx];
}
// XOR swizzle for 64-wide bf16 LDS tiles (row stride 128B): spreads the 16
// same-column rows across 8 distinct 16B slots (m214 G4 fix).
__device__ __forceinline__ int swz(int row, int kbyte) {
    return row * 128 + (kbyte ^ ((row & 7) << 4));
}

// ---------------------------------------------------------------------------
// dtype detection (adj int64? mask byte-packed?)
// ---------------------------------------------------------------------------
__global__ __launch_bounds__(256) void k_detect(const int* __restrict__ adj,
                                                const unsigned int* __restrict__ mask,
                                                int* __restrict__ flags)
{
    __shared__ int s_odd, s_big;
    if (threadIdx.x == 0) { s_odd = 0; s_big = 0; }
    __syncthreads();
    int odd = 0, big = 0;
    for (int i = threadIdx.x; i < 512; i += 256) {
        if (adj[2 * i + 1] != 0) odd = 1;
        if (mask[i] > 1u) big = 1;
    }
    if (odd) atomicOr(&s_odd, 1);
    if (big) atomicOr(&s_big, 1);
    __syncthreads();
    if (threadIdx.x == 0) {
        flags[0] = s_odd ? 0 : 1;   // 1 -> adj is int64
        flags[1] = s_big ? 1 : 0;   // 1 -> mask is bytes
    }
}

// ---------------------------------------------------------------------------
// QKV projections. z==2 (V) additionally emits ONLY the transposed bf16 copy
// Vt[z][d][s] used by the MFMA ctx kernel.
// ---------------------------------------------------------------------------
__global__ __launch_bounds__(256) void k_proj(
    const float* __restrict__ query, const float* __restrict__ key, const float* __restrict__ value,
    const float* __restrict__ Wq, const float* __restrict__ bq,
    const float* __restrict__ Wk, const float* __restrict__ bk,
    const float* __restrict__ Wv, const float* __restrict__ bv,
    float* __restrict__ ws, unsigned short* __restrict__ Vt)
{
    const int z = blockIdx.z;
    const float* A    = (z == 0) ? query : (z == 1) ? key : value;
    const float* W    = (z == 0) ? Wq : (z == 1) ? Wk : Wv;
    const float* bias = (z == 0) ? bq : (z == 1) ? bk : bv;
    float* out = ws + ((z == 0) ? OFF_Q : OFF_K);   // unused for z==2

    const int n0 = blockIdx.x * 64;
    const int m0 = blockIdx.y * 64;
    __shared__ float As[64][33];
    __shared__ float Bs[32][64];
    const int tid = threadIdx.x;
    const int tm = tid & 15, tn = tid >> 4;
    float acc[4][4] = {};

    for (int k0 = 0; k0 < FF; k0 += 32) {
#pragma unroll
        for (int i = 0; i < 8; i++) {
            int idx = tid + i * 256;
            As[idx >> 5][idx & 31] = A[(size_t)(m0 + (idx >> 5)) * FF + k0 + (idx & 31)];
        }
#pragma unroll
        for (int i = 0; i < 8; i++) {
            int idx = tid + i * 256;
            Bs[idx >> 6][idx & 63] = W[(size_t)(k0 + (idx >> 6)) * HDIM + n0 + (idx & 63)];
        }
        __syncthreads();
#pragma unroll
        for (int kk = 0; kk < 32; kk++) {
            float a[4];
#pragma unroll
            for (int i = 0; i < 4; i++) a[i] = As[tm * 4 + i][kk];
            const float4 b4 = *(const float4*)&Bs[kk][tn * 4];
            const float bb[4] = {b4.x, b4.y, b4.z, b4.w};
#pragma unroll
            for (int i = 0; i < 4; i++)
#pragma unroll
                for (int j = 0; j < 4; j++)
                    acc[i][j] += a[i] * bb[j];
        }
        __syncthreads();
    }

    const int h = n0 >> 6;
    const int d0 = tn * 4;
#pragma unroll
    for (int i = 0; i < 4; i++) {
        int m = m0 + tm * 4 + i;
        int b = m >> 9, s = m & 511;
        float v0 = acc[i][0] + bias[n0 + d0 + 0];
        float v1 = acc[i][1] + bias[n0 + d0 + 1];
        float v2 = acc[i][2] + bias[n0 + d0 + 2];
        float v3 = acc[i][3] + bias[n0 + d0 + 3];
        if (z == 2) {
            const size_t zb = (size_t)(b * HH + h) * DD;
            Vt[(zb + d0 + 0) * SS + s] = f2bf(v0);
            Vt[(zb + d0 + 1) * SS + s] = f2bf(v1);
            Vt[(zb + d0 + 2) * SS + s] = f2bf(v2);
            Vt[(zb + d0 + 3) * SS + s] = f2bf(v3);
        } else {
            *(float4*)&out[((size_t)(b * HH + h) * SS + s) * DD + d0] =
                make_float4(v0, v1, v2, v3);
        }
    }
}

// ---------------------------------------------------------------------------
// qe[b,h,q,r] = q[b,h,q,:] . emb_k[r,:]
// ---------------------------------------------------------------------------
__global__ __launch_bounds__(256) void k_qe(const float* __restrict__ q,
                                            const float* __restrict__ emb_k,
                                            float* __restrict__ qe)
{
    __shared__ float Es[64][65];
    __shared__ float Qs[16][64];
    const int tid = threadIdx.x;
    const int row0 = blockIdx.x * 16;
#pragma unroll
    for (int i = 0; i < 16; i++) {
        int idx = tid + i * 256;
        Es[idx >> 6][idx & 63] = emb_k[idx];
    }
#pragma unroll
    for (int i = 0; i < 4; i++) {
        int idx = tid + i * 256;
        Qs[idx >> 6][idx & 63] = q[(size_t)row0 * 64 + idx];
    }
    __syncthreads();
    const int r = tid & 63;
    const int wid = tid >> 6;
#pragma unroll
    for (int i = 0; i < 4; i++) {
        int row = wid * 4 + i;
        float acc = 0.f;
#pragma unroll
        for (int d = 0; d < 64; d++)
            acc += Qs[row][d] * Es[r][d];
        qe[(size_t)(row0 + row) * 64 + r] = acc;
    }
}

// ---------------------------------------------------------------------------
// Fused scores + bias-gather + mask + softmax + attn-write + bucket-reduce.
// Block: 512 threads (8 waves). Wave rg owns 4 complete rows (rg*4..rg*4+3);
// lane cg owns cols {cg + 64*jj}. Logits live in registers; softmax is pure
// in-wave shuffle reduction. K streamed in 4 LDS quarters of 128 cols.
// ---------------------------------------------------------------------------
__global__ __launch_bounds__(512, 2) void k_attn(
    const float* __restrict__ q, const float* __restrict__ kmat,
    const float* __restrict__ qe, const int* __restrict__ adj,
    const void* __restrict__ mask, const int* __restrict__ flags,
    float* __restrict__ attn, float* __restrict__ w)
{
    const int z = blockIdx.y;          // b*8 + h
    const int b = z >> 3;
    const int q0 = blockIdx.x * 32;
    const int tid = threadIdx.x;
    const int rg = tid >> 6;           // wave 0..7
    const int cg = tid & 63;           // lane

    __shared__ float Qs[32][68];       // float4-aligned stride
    __shared__ float QEs[32][65];
    __shared__ float Ks[128][65];
    __shared__ float w_s[32][64];

    // ---- load Q/QE tiles, zero w_s ----
    {
        int idx = tid;                 // 512 float4s, 512 threads
        int r = idx >> 4, d4 = (idx & 15) * 4;
        *(float4*)&Qs[r][d4] = *(const float4*)&q[((size_t)z * SS + q0 + r) * DD + d4];
        float4 e4 = *(const float4*)&qe[((size_t)z * SS + q0 + r) * RR + d4];
        QEs[r][d4 + 0] = e4.x; QEs[r][d4 + 1] = e4.y;
        QEs[r][d4 + 2] = e4.z; QEs[r][d4 + 3] = e4.w;
    }
    for (int i = tid; i < 2048; i += 512) ((float*)w_s)[i] = 0.f;

    const int f64 = flags[0], fbyte = flags[1];
    int msk[8];
#pragma unroll
    for (int jj = 0; jj < 8; jj++)
        msk[jj] = load_mask_v(mask, b * SS + cg + jj * 64, fbyte);

    int av[4][8];
#pragma unroll
    for (int i = 0; i < 4; i++) {
        const long arow = ((long)b * SS + q0 + rg * 4 + i) * SS;
#pragma unroll
        for (int jj = 0; jj < 8; jj++)
            av[i][jj] = load_adj_v(adj, arow + cg + jj * 64, f64);
    }

    float acc[4][8];
#pragma unroll
    for (int i = 0; i < 4; i++)
#pragma unroll
        for (int jj = 0; jj < 8; jj++) acc[i][jj] = 0.f;

    // ---- QK^T over 4 K-quarters (fully unrolled -> static acc indices) ----
#pragma unroll
    for (int qt = 0; qt < 4; qt++) {
        __syncthreads();
        for (int idx = tid; idx < 2048; idx += 512) {   // 128 rows x 16 float4
            int cl = idx >> 4, d4 = (idx & 15) * 4;
            float4 k4 = *(const float4*)&kmat[((size_t)z * SS + qt * 128 + cl) * DD + d4];
            Ks[cl][d4 + 0] = k4.x; Ks[cl][d4 + 1] = k4.y;
            Ks[cl][d4 + 2] = k4.z; Ks[cl][d4 + 3] = k4.w;
        }
        __syncthreads();
#pragma unroll 4
        for (int d0 = 0; d0 < 64; d0 += 4) {
            float4 q4[4];
#pragma unroll
            for (int i = 0; i < 4; i++) q4[i] = *(const float4*)&Qs[rg * 4 + i][d0];
#pragma unroll
            for (int jj2 = 0; jj2 < 2; jj2++) {
                const float* kp = &Ks[jj2 * 64 + cg][d0];
                const float k0 = kp[0], k1 = kp[1], k2 = kp[2], k3 = kp[3];
#pragma unroll
                for (int i = 0; i < 4; i++)
                    acc[i][qt * 2 + jj2] += q4[i].x * k0 + q4[i].y * k1
                                          + q4[i].z * k2 + q4[i].w * k3;
            }
        }
    }

    // ---- bias gather + scale + mask ----
    const float NEG = -__builtin_huge_valf();
#pragma unroll
    for (int i = 0; i < 4; i++)
#pragma unroll
        for (int jj = 0; jj < 8; jj++) {
            float v = (acc[i][jj] + QEs[rg * 4 + i][av[i][jj]]) * 0.125f;
            acc[i][jj] = msk[jj] ? NEG : v;
        }

    // ---- per-row softmax (in-wave), attn write, bucket atomics ----
#pragma unroll
    for (int i = 0; i < 4; i++) {
        float m = acc[i][0];
#pragma unroll
        for (int jj = 1; jj < 8; jj++) m = fmaxf(m, acc[i][jj]);
#pragma unroll
        for (int off = 32; off >= 1; off >>= 1) m = fmaxf(m, __shfl_xor(m, off, 64));
        float s = 0.f;
#pragma unroll
        for (int jj = 0; jj < 8; jj++) {
            float e = __expf(acc[i][jj] - m);
            acc[i][jj] = e; s += e;
        }
#pragma unroll
        for (int off = 32; off >= 1; off >>= 1) s += __shfl_xor(s, off, 64);
        const float inv = 1.f / s;
        const size_t arow = ((size_t)z * SS + q0 + rg * 4 + i) * SS;
#pragma unroll
        for (int jj = 0; jj < 8; jj++) {
            float p = acc[i][jj] * inv;
            attn[arow + cg + jj * 64] = p;
            atomicAdd(&w_s[rg * 4 + i][av[i][jj]], p);
        }
    }
    __syncthreads();
    for (int idx = tid; idx < 2048; idx += 512)
        w[((size_t)z * SS + q0) * RR + idx] = ((const float*)w_s)[idx];
}

// ---------------------------------------------------------------------------
// ctx = attn @ V + w @ emb_v, bf16 MFMA (16x16x32). Block 64(q) x 64(d),
// 4 waves in 2x2, K-steps of 64 (8 attn steps + 1 w/emb_v step).
// A_s row-major [64][64] bf16, Bt_s holds B^T [dd][k]; both XOR-swizzled.
// ---------------------------------------------------------------------------
__global__ __launch_bounds__(256, 2) void k_ctx(
    const float* __restrict__ attn, const unsigned short* __restrict__ Vt,
    const float* __restrict__ w, const float* __restrict__ emb_v,
    float* __restrict__ ctx)
{
    const int z = blockIdx.y, b = z >> 3, h = z & 7;
    const int q0 = blockIdx.x * 64;
    const int tid = threadIdx.x;
    const int wid = tid >> 6, lane = tid & 63;
    const int wr = wid >> 1, wc = wid & 1;       // wave tile: 32 rows x 32 cols

    __shared__ unsigned short A_s[64 * 64];
    __shared__ unsigned short B_s[64 * 64];
    char* Ab = (char*)A_s;
    char* Bb = (char*)B_s;

    f32x4 acc[2][2];
#pragma unroll
    for (int mi = 0; mi < 2; mi++)
#pragma unroll
        for (int ni = 0; ni < 2; ni++)
#pragma unroll
            for (int e = 0; e < 4; e++) acc[mi][ni][e] = 0.f;

    const int sr = tid >> 2;                 // staging row (0..63)
    const int skc = (tid & 3) * 16;          // k-chunk base (elements)

    for (int t = 0; t < 9; t++) {
        const int k0 = t * 64;
        const bool tail = (t == 8);

        // issue global loads early (regs), consume after barrier
        float4 a4[4];
        bf16x8 bv0, bv1;
        {
            const float* ap = tail
                ? &w[((size_t)z * SS + q0 + sr) * RR + skc]
                : &attn[((size_t)z * SS + q0 + sr) * SS + k0 + skc];
#pragma unroll
            for (int u = 0; u < 4; u++) a4[u] = *(const float4*)(ap + u * 4);
            if (!tail) {
                const unsigned short* bp = &Vt[((size_t)z * DD + sr) * SS + k0 + skc];
                bv0 = *(const bf16x8*)(bp);
                bv1 = *(const bf16x8*)(bp + 8);
            } else {
                // B = emb_v[R][dd] transposed: B^T[dd=sr][r2 = skc..skc+15]
#pragma unroll
                for (int u = 0; u < 8; u++) {
                    bv0[u] = (short)f2bf(emb_v[(size_t)(skc + u) * DD + sr]);
                    bv1[u] = (short)f2bf(emb_v[(size_t)(skc + 8 + u) * DD + sr]);
                }
            }
        }
        __syncthreads();   // previous iteration's fragment reads complete
        {
            bf16x8 pa0, pa1;
#pragma unroll
            for (int u = 0; u < 4; u++) {
                unsigned short e0 = f2bf(a4[u].x), e1 = f2bf(a4[u].y);
                unsigned short e2 = f2bf(a4[u].z), e3 = f2bf(a4[u].w);
                if (u < 2) { pa0[u*4+0]=(short)e0; pa0[u*4+1]=(short)e1; pa0[u*4+2]=(short)e2; pa0[u*4+3]=(short)e3; }
                else { pa1[(u-2)*4+0]=(short)e0; pa1[(u-2)*4+1]=(short)e1; pa1[(u-2)*4+2]=(short)e2; pa1[(u-2)*4+3]=(short)e3; }
            }
            *(bf16x8*)(Ab + swz(sr, skc * 2))      = pa0;
            *(bf16x8*)(Ab + swz(sr, skc * 2 + 16)) = pa1;
            *(bf16x8*)(Bb + swz(sr, skc * 2))      = bv0;
            *(bf16x8*)(Bb + swz(sr, skc * 2 + 16)) = bv1;
        }
        __syncthreads();   // staging visible

        bf16x8 fa[2][2], fb[2][2];
        const int kfrag = (lane >> 4) * 16;   // byte offset of this lane's 8 bf16
#pragma unroll
        for (int mi = 0; mi < 2; mi++) {
            const int row = wr * 32 + mi * 16 + (lane & 15);
#pragma unroll
            for (int ks = 0; ks < 2; ks++)
                fa[mi][ks] = *(const bf16x8*)(Ab + swz(row, ks * 64 + kfrag));
        }
#pragma unroll
        for (int ni = 0; ni < 2; ni++) {
            const int dd = wc * 32 + ni * 16 + (lane & 15);
#pragma unroll
            for (int ks = 0; ks < 2; ks++)
                fb[ni][ks] = *(const bf16x8*)(Bb + swz(dd, ks * 64 + kfrag));
        }
#pragma unroll
        for (int ks = 0; ks < 2; ks++)
#pragma unroll
            for (int mi = 0; mi < 2; mi++)
#pragma unroll
                for (int ni = 0; ni < 2; ni++)
                    acc[mi][ni] = __builtin_amdgcn_mfma_f32_16x16x32_bf16(
                        fa[mi][ks], fb[ni][ks], acc[mi][ni], 0, 0, 0);
    }

    // epilogue: C/D layout col = lane&15, row = (lane>>4)*4 + e  [m89-verified]
#pragma unroll
    for (int mi = 0; mi < 2; mi++)
#pragma unroll
        for (int ni = 0; ni < 2; ni++) {
            const int col = wc * 32 + ni * 16 + (lane & 15);
#pragma unroll
            for (int e = 0; e < 4; e++) {
                const int row = q0 + wr * 32 + mi * 16 + (lane >> 4) * 4 + e;
                ctx[((size_t)b * SS + row) * HDIM + h * DD + col] = acc[mi][ni][e];
            }
        }
}

// ---------------------------------------------------------------------------
// out = ctx(2048x512) @ Wo(512x512) + bo
// ---------------------------------------------------------------------------
__global__ __launch_bounds__(256) void k_out(
    const float* __restrict__ ctx, const float* __restrict__ Wo,
    const float* __restrict__ bo, float* __restrict__ out)
{
    const int n0 = blockIdx.x * 64;
    const int m0 = blockIdx.y * 64;
    __shared__ float As[64][33];
    __shared__ float Bs[32][64];
    const int tid = threadIdx.x;
    const int tm = tid & 15, tn = tid >> 4;
    float acc[4][4] = {};

    for (int k0 = 0; k0 < HDIM; k0 += 32) {
#pragma unroll
        for (int i = 0; i < 8; i++) {
            int idx = tid + i * 256;
            As[idx >> 5][idx & 31] = ctx[(size_t)(m0 + (idx >> 5)) * HDIM + k0 + (idx & 31)];
        }
#pragma unroll
        for (int i = 0; i < 8; i++) {
            int idx = tid + i * 256;
            Bs[idx >> 6][idx & 63] = Wo[(size_t)(k0 + (idx >> 6)) * OO + n0 + (idx & 63)];
        }
        __syncthreads();
#pragma unroll
        for (int kk = 0; kk < 32; kk++) {
            float a[4];
#pragma unroll
            for (int i = 0; i < 4; i++) a[i] = As[tm * 4 + i][kk];
            const float4 b4 = *(const float4*)&Bs[kk][tn * 4];
            const float bb[4] = {b4.x, b4.y, b4.z, b4.w};
#pragma unroll
            for (int i = 0; i < 4; i++)
#pragma unroll
                for (int j = 0; j < 4; j++)
                    acc[i][j] += a[i] * bb[j];
        }
        __syncthreads();
    }

#pragma unroll
    for (int i = 0; i < 4; i++) {
        int m = m0 + tm * 4 + i;
        float4 o;
        o.x = acc[i][0] + bo[n0 + tn * 4 + 0];
        o.y = acc[i][1] + bo[n0 + tn * 4 + 1];
        o.z = acc[i][2] + bo[n0 + tn * 4 + 2];
        o.w = acc[i][3] + bo[n0 + tn * 4 + 3];
        *(float4*)&out[(size_t)m * OO + n0 + tn * 4] = o;
    }
}

extern "C" void kernel_launch(void* const* d_in, const int* in_sizes, int n_in,
                              void* d_out, int out_size, void* d_ws, size_t ws_size,
                              hipStream_t stream)
{
    const float* key   = (const float*)d_in[0];
    const float* value = (const float*)d_in[1];
    const float* query = (const float*)d_in[2];
    const void*  mask  = d_in[3];
    const int*   adj   = (const int*)d_in[4];
    const float* Wq    = (const float*)d_in[5];
    const float* bq    = (const float*)d_in[6];
    const float* Wk    = (const float*)d_in[7];
    const float* bk    = (const float*)d_in[8];
    const float* Wv    = (const float*)d_in[9];
    const float* bv    = (const float*)d_in[10];
    const float* Wo    = (const float*)d_in[11];
    const float* bo    = (const float*)d_in[12];
    const float* emb_k = (const float*)d_in[13];
    const float* emb_v = (const float*)d_in[14];

    float* ws   = (float*)d_ws;
    float* outp = (float*)d_out;                       // (B,S,OUT)
    float* attn = outp + (size_t)BB * SS * OO;         // (B,H,S,S) tuple output #2
    unsigned short* Vt = (unsigned short*)(ws + OFF_VT);
    int* flags = (int*)(ws + OFF_FLAGS);

    k_detect<<<1, 256, 0, stream>>>(adj, (const unsigned int*)mask, flags);
    k_proj  <<<dim3(8, 32, 3), 256, 0, stream>>>(query, key, value,
                                                 Wq, bq, Wk, bk, Wv, bv, ws, Vt);
    k_qe    <<<1024, 256, 0, stream>>>(ws + OFF_Q, emb_k, ws + OFF_QE);
    k_attn  <<<dim3(16, 32), 512, 0, stream>>>(ws + OFF_Q, ws + OFF_K, ws + OFF_QE,
                                               adj, mask, flags, attn, ws + OFF_W);
    k_ctx   <<<dim3(8, 32), 256, 0, stream>>>(attn, Vt, ws + OFF_W, emb_v,
                                              ws + OFF_CTX);
    k_out   <<<dim3(8, 32), 256, 0, stream>>>(ws + OFF_CTX, Wo, bo, outp);
}

// Round 3
// 211.516 us; speedup vs baseline: 2.0723x; 1.3527x over previous
//
#include <hip/hip_runtime.h>
#include <hip/hip_bf16.h>
#include <math.h>

#define BB 4
#define SS 512
#define FF 512
#define HH 8
#define DD 64
#define RR 64
#define OO 512

typedef _Float16 f16;
typedef __attribute__((ext_vector_type(8))) _Float16 f16x8;
typedef __attribute__((ext_vector_type(4))) _Float16 f16x4;
typedef __attribute__((ext_vector_type(4))) float f32x4;

// ws byte offsets
#define WS_QH    0u
#define WS_KH    (2u<<20)
#define WS_VTH   (4u<<20)
#define WS_CTXH  (6u<<20)
#define WS_QE    (8u<<20)
#define WS_WT    (12u<<20)          // 4 x 512KB: WqT, WkT, WvT, WoT (f16)
#define WS_EVT   (14u<<20)          // emb_v^T f16 (8KB)
#define WS_FLAGS ((14u<<20) + 8192u)

// XOR swizzle: spread same-16B-column rows across 8 bank slots (T2 / G4)
__device__ __forceinline__ int swz128(int row, int b)  { return row*128  + (b ^ ((row&7)<<4)); }
__device__ __forceinline__ int swz256(int row, int b)  { return row*256  + (b ^ ((row&7)<<4)); }
__device__ __forceinline__ int swz1024(int row, int b) { return row*1024 + (b ^ ((row&7)<<4)); }

// ---------------------------------------------------------------------------
// dtype detection (adj int64? mask byte-packed?)
// ---------------------------------------------------------------------------
__global__ __launch_bounds__(256) void k_detect(const int* __restrict__ adj,
                                                const unsigned int* __restrict__ mask,
                                                int* __restrict__ flags)
{
    __shared__ int s_odd, s_big;
    if (threadIdx.x == 0) { s_odd = 0; s_big = 0; }
    __syncthreads();
    int odd = 0, big = 0;
    for (int i = threadIdx.x; i < 512; i += 256) {
        if (adj[2*i + 1] != 0) odd = 1;
        if (mask[i] > 1u) big = 1;
    }
    if (odd) atomicOr(&s_odd, 1);
    if (big) atomicOr(&s_big, 1);
    __syncthreads();
    if (threadIdx.x == 0) {
        flags[0] = s_odd ? 0 : 1;   // 1 -> adj is int64
        flags[1] = s_big ? 1 : 0;   // 1 -> mask is bytes
    }
}

// ---------------------------------------------------------------------------
// Prep: transpose weights to f16  WT[z][n][k] = W[k][n]; evt[d][r] = emb_v[r][d]
// ---------------------------------------------------------------------------
__global__ __launch_bounds__(256) void k_prep(
    const float* __restrict__ Wq, const float* __restrict__ Wk,
    const float* __restrict__ Wv, const float* __restrict__ Wo,
    const float* __restrict__ emb_v, f16* __restrict__ WT, f16* __restrict__ evt)
{
    const int z = blockIdx.z;
    __shared__ float tile[64][65];
    const int tid = threadIdx.x;
    const int r = tid >> 2, c4 = (tid & 3) * 16;
    if (z < 4) {
        const float* W = (z==0)?Wq:(z==1)?Wk:(z==2)?Wv:Wo;
        f16* T = WT + (size_t)z * 262144;
        const int k0 = blockIdx.y * 64, n0 = blockIdx.x * 64;
#pragma unroll
        for (int u = 0; u < 4; ++u) {
            const float4 w4 = *(const float4*)&W[(size_t)(k0 + r)*512 + n0 + c4 + u*4];
            tile[r][c4+u*4+0] = w4.x; tile[r][c4+u*4+1] = w4.y;
            tile[r][c4+u*4+2] = w4.z; tile[r][c4+u*4+3] = w4.w;
        }
        __syncthreads();
        f16x8 v0, v1;
#pragma unroll
        for (int j = 0; j < 8; ++j) { v0[j] = (f16)tile[c4+j][r]; v1[j] = (f16)tile[c4+8+j][r]; }
        f16* dst = &T[(size_t)(n0 + r)*512 + k0 + c4];
        *(f16x8*)dst = v0; *(f16x8*)(dst + 8) = v1;
    } else {
        if (blockIdx.x | blockIdx.y) return;
#pragma unroll
        for (int u = 0; u < 4; ++u) {
            const float4 w4 = *(const float4*)&emb_v[(size_t)r*64 + c4 + u*4];
            tile[r][c4+u*4+0] = w4.x; tile[r][c4+u*4+1] = w4.y;
            tile[r][c4+u*4+2] = w4.z; tile[r][c4+u*4+3] = w4.w;
        }
        __syncthreads();
        f16x8 v0, v1;
#pragma unroll
        for (int j = 0; j < 8; ++j) { v0[j] = (f16)tile[c4+j][r]; v1[j] = (f16)tile[c4+8+j][r]; }
        f16* dst = &evt[(size_t)r*64 + c4];
        *(f16x8*)dst = v0; *(f16x8*)(dst + 8) = v1;
    }
}

// ---------------------------------------------------------------------------
// QKV projection, f16 MFMA. A(2048x512) f32 @ WT^T + b. Emits q,k as f16
// [zb][s][64]; V as f16 transposed [zb][64][s].
// ---------------------------------------------------------------------------
__global__ __launch_bounds__(256) void k_proj(
    const float* __restrict__ query, const float* __restrict__ key, const float* __restrict__ value,
    const f16* __restrict__ WT,
    const float* __restrict__ bq, const float* __restrict__ bk, const float* __restrict__ bv,
    f16* __restrict__ qh, f16* __restrict__ kh, f16* __restrict__ vth)
{
    const int z = blockIdx.z;
    const float* A    = (z == 0) ? query : (z == 1) ? key : value;
    const f16*   Bt   = WT + (size_t)z * 262144;
    const float* bias = (z == 0) ? bq : (z == 1) ? bk : bv;

    const int n0 = blockIdx.x * 64;
    const int m0 = blockIdx.y * 64;
    __shared__ char Ab[64*128];
    __shared__ char Bb[64*128];
    const int tid = threadIdx.x;
    const int wid = tid >> 6, l = tid & 63;
    const int wr = wid >> 1, wc = wid & 1;
    const int lr = l & 15, lg = l >> 4;
    const int sr = tid >> 2, sc = (tid & 3) * 16;

    f32x4 acc[2][2];
#pragma unroll
    for (int mi = 0; mi < 2; ++mi)
#pragma unroll
        for (int ni = 0; ni < 2; ++ni) acc[mi][ni] = (f32x4){0.f,0.f,0.f,0.f};

    for (int k0 = 0; k0 < 512; k0 += 64) {
        float4 a4[4];
#pragma unroll
        for (int u = 0; u < 4; ++u)
            a4[u] = *(const float4*)&A[(size_t)(m0 + sr)*512 + k0 + sc + u*4];
        f16x8 b0 = *(const f16x8*)&Bt[(size_t)(n0 + sr)*512 + k0 + sc];
        f16x8 b1 = *(const f16x8*)&Bt[(size_t)(n0 + sr)*512 + k0 + sc + 8];
        __syncthreads();
        f16x8 pa0, pa1;
        pa0[0]=(f16)a4[0].x; pa0[1]=(f16)a4[0].y; pa0[2]=(f16)a4[0].z; pa0[3]=(f16)a4[0].w;
        pa0[4]=(f16)a4[1].x; pa0[5]=(f16)a4[1].y; pa0[6]=(f16)a4[1].z; pa0[7]=(f16)a4[1].w;
        pa1[0]=(f16)a4[2].x; pa1[1]=(f16)a4[2].y; pa1[2]=(f16)a4[2].z; pa1[3]=(f16)a4[2].w;
        pa1[4]=(f16)a4[3].x; pa1[5]=(f16)a4[3].y; pa1[6]=(f16)a4[3].z; pa1[7]=(f16)a4[3].w;
        *(f16x8*)(Ab + swz128(sr, sc*2))    = pa0;
        *(f16x8*)(Ab + swz128(sr, sc*2+16)) = pa1;
        *(f16x8*)(Bb + swz128(sr, sc*2))    = b0;
        *(f16x8*)(Bb + swz128(sr, sc*2+16)) = b1;
        __syncthreads();
        f16x8 fa[2][2], fb[2][2];
#pragma unroll
        for (int mi = 0; mi < 2; ++mi) {
            const int row = wr*32 + mi*16 + lr;
#pragma unroll
            for (int ks = 0; ks < 2; ++ks)
                fa[mi][ks] = *(const f16x8*)(Ab + swz128(row, ks*64 + lg*16));
        }
#pragma unroll
        for (int ni = 0; ni < 2; ++ni) {
            const int row = wc*32 + ni*16 + lr;
#pragma unroll
            for (int ks = 0; ks < 2; ++ks)
                fb[ni][ks] = *(const f16x8*)(Bb + swz128(row, ks*64 + lg*16));
        }
#pragma unroll
        for (int ks = 0; ks < 2; ++ks)
#pragma unroll
            for (int mi = 0; mi < 2; ++mi)
#pragma unroll
                for (int ni = 0; ni < 2; ++ni)
                    acc[mi][ni] = __builtin_amdgcn_mfma_f32_16x16x32_f16(
                        fa[mi][ks], fb[ni][ks], acc[mi][ni], 0, 0, 0);
    }

#pragma unroll
    for (int ni = 0; ni < 2; ++ni) {
        const int n = n0 + wc*32 + ni*16 + lr;
        const float bv_ = bias[n];
        const int h = n >> 6, d = n & 63;
#pragma unroll
        for (int mi = 0; mi < 2; ++mi)
#pragma unroll
            for (int e = 0; e < 4; ++e) {
                const int m = m0 + wr*32 + mi*16 + lg*4 + e;
                const int b = m >> 9, s = m & 511;
                const f16 v = (f16)(acc[mi][ni][e] + bv_);
                if (z == 2)       vth[((size_t)(b*HH + h)*DD + d)*SS + s] = v;
                else if (z == 1)  kh [((size_t)(b*HH + h)*SS + s)*DD + d] = v;
                else              qh [((size_t)(b*HH + h)*SS + s)*DD + d] = v;
            }
    }
}

// ---------------------------------------------------------------------------
// qe[zb,s,r] = q[zb,s,:] . emb_k[r,:]   (f32 out, q from f16)
// ---------------------------------------------------------------------------
__global__ __launch_bounds__(256) void k_qe(const f16* __restrict__ qh,
                                            const float* __restrict__ emb_k,
                                            float* __restrict__ qe)
{
    __shared__ float Es[64][65];
    __shared__ float Qs[16][64];
    const int tid = threadIdx.x;
    const int row0 = blockIdx.x * 16;
#pragma unroll
    for (int i = 0; i < 16; ++i) {
        const int idx = tid + i*256;
        Es[idx >> 6][idx & 63] = emb_k[idx];
    }
#pragma unroll
    for (int i = 0; i < 4; ++i) {
        const int idx = tid + i*256;
        Qs[idx >> 6][idx & 63] = (float)qh[(size_t)row0*64 + idx];
    }
    __syncthreads();
    const int r = tid & 63;
    const int wid = tid >> 6;
#pragma unroll
    for (int i = 0; i < 4; ++i) {
        const int row = wid*4 + i;
        float a = 0.f;
#pragma unroll
        for (int d = 0; d < 64; ++d) a += Qs[row][d] * Es[r][d];
        qe[(size_t)(row0 + row)*64 + r] = a;
    }
}

// ---------------------------------------------------------------------------
// Fully fused attention: QK^T (swapped MFMA -> lane-local rows) + rel-pos bias
// gather + mask + softmax + attn write + bucket-reduce + PV MFMA + w@emb_v.
// Block = 256 thr (4 waves), 16 q-rows x one (b,h). Each wave owns a 128-k
// range for QK and a 16-d column slice for PV.
// ---------------------------------------------------------------------------
__global__ __launch_bounds__(256, 3) void k_attn(
    const f16* __restrict__ qh, const f16* __restrict__ kh, const f16* __restrict__ vth,
    const float* __restrict__ qe, const int* __restrict__ adj,
    const void* __restrict__ mask, const int* __restrict__ flags,
    const f16* __restrict__ evt, float* __restrict__ attn, f16* __restrict__ ctxh)
{
    const int z = blockIdx.y, b = z >> 3, h = z & 7;
    const int q0 = blockIdx.x * 16;
    const int tid = threadIdx.x, w = tid >> 6, l = tid & 63;
    const int ql = l & 15, g = l >> 4;

    __shared__ char KVb[16384];             // K panel [128][64] / V^T panel [64][128]
    __shared__ char Pb[16384];              // P f16 [16][512], swz1024 rows
    __shared__ char Qb[2048];               // Q f16 [16][64], swz128
    __shared__ char P2b[2048];              // w f16 [16][64], swz128
    __shared__ float QE_s[16][65];
    __shared__ unsigned char adj8[16][516]; // adj | mask<<7
    __shared__ float w_s[16][65];
    __shared__ float red_m[4][16], red_s[4][16];

    const int f64 = flags[0], fbyte = flags[1];

    // ---- phase 0: stage Q, QE, adj+mask, zero w_s ----
    if (tid < 64) {
        const int r = tid >> 2, cb = (tid & 3) * 16;
        const f16* src = &qh[((size_t)z*SS + q0 + r)*DD + cb];
        const f16x8 v0 = *(const f16x8*)src;
        const f16x8 v1 = *(const f16x8*)(src + 8);
        *(f16x8*)(Qb + swz128(r, cb*2))      = v0;
        *(f16x8*)(Qb + swz128(r, cb*2 + 16)) = v1;
    }
    for (int i = tid; i < 1024; i += 256)
        QE_s[i >> 6][i & 63] = qe[((size_t)z*SS + q0 + (i >> 6))*RR + (i & 63)];
    for (int i = tid; i < 8192; i += 256) {
        const int qq = i >> 9, k = i & 511;
        const long idx = ((long)(b*SS) + q0 + qq)*SS + k;
        const int av = f64 ? adj[2*idx] : adj[idx];
        const int mk = fbyte ? (int)((const unsigned char*)mask)[b*SS + k]
                             : ((const int*)mask)[b*SS + k];
        adj8[qq][k] = (unsigned char)((av & 63) | (mk ? 128 : 0));
    }
    for (int i = tid; i < 16*65; i += 256) (&w_s[0][0])[i] = 0.f;
    __syncthreads();

    // ---- QK^T: S^T tiles via mfma(K, Q); lane holds q-row = l&15 ----
    f32x4 acc[8];
#pragma unroll
    for (int i = 0; i < 8; ++i) acc[i] = (f32x4){0.f,0.f,0.f,0.f};

    for (int p = 0; p < 4; ++p) {
        f16x8 kv[4];
        {
            const int r = tid >> 1, cb = (tid & 1) * 32;
            const f16* src = &kh[((size_t)z*SS + p*128 + r)*DD + cb];
#pragma unroll
            for (int u = 0; u < 4; ++u) kv[u] = *(const f16x8*)(src + u*8);
        }
        __syncthreads();                      // prev panel fragment reads done
        {
            const int r = tid >> 1, cb = (tid & 1) * 32;
#pragma unroll
            for (int u = 0; u < 4; ++u)
                *(f16x8*)(KVb + swz128(r, (cb + u*8)*2)) = kv[u];
        }
        __syncthreads();
        const f16x8 fb0 = *(const f16x8*)(Qb + swz128(ql, g*16));
        const f16x8 fb1 = *(const f16x8*)(Qb + swz128(ql, 64 + g*16));
#pragma unroll
        for (int t = 0; t < 2; ++t) {
            const int row = w*32 + t*16 + ql;
            const f16x8 fa0 = *(const f16x8*)(KVb + swz128(row, g*16));
            const f16x8 fa1 = *(const f16x8*)(KVb + swz128(row, 64 + g*16));
            acc[p*2+t] = __builtin_amdgcn_mfma_f32_16x16x32_f16(fa0, fb0, acc[p*2+t], 0,0,0);
            acc[p*2+t] = __builtin_amdgcn_mfma_f32_16x16x32_f16(fa1, fb1, acc[p*2+t], 0,0,0);
        }
    }

    // ---- bias gather + mask + row max ----
    unsigned int avw[8];
    float m_w = -1e30f;
#pragma unroll
    for (int pt = 0; pt < 8; ++pt) {
        const int k0 = (pt >> 1)*128 + w*32 + (pt & 1)*16 + g*4;
        avw[pt] = *(const unsigned int*)&adj8[ql][k0];
#pragma unroll
        for (int e = 0; e < 4; ++e) {
            const unsigned a = (avw[pt] >> (8*e)) & 255u;
            float s = (acc[pt][e] + QE_s[ql][a & 63]) * 0.125f;
            s = (a & 128u) ? -1e30f : s;
            acc[pt][e] = s;
            m_w = fmaxf(m_w, s);
        }
    }
    m_w = fmaxf(m_w, __shfl_xor(m_w, 16, 64));
    m_w = fmaxf(m_w, __shfl_xor(m_w, 32, 64));
    float s_w = 0.f;
#pragma unroll
    for (int pt = 0; pt < 8; ++pt)
#pragma unroll
        for (int e = 0; e < 4; ++e) {
            const float ev = __expf(acc[pt][e] - m_w);
            acc[pt][e] = ev;
            s_w += ev;
        }
    s_w += __shfl_xor(s_w, 16, 64);
    s_w += __shfl_xor(s_w, 32, 64);
    if (l < 16) { red_m[w][ql] = m_w; red_s[w][ql] = s_w; }
    __syncthreads();
    float M = red_m[0][ql];
#pragma unroll
    for (int j = 1; j < 4; ++j) M = fmaxf(M, red_m[j][ql]);
    float T = 0.f;
#pragma unroll
    for (int j = 0; j < 4; ++j) T += red_s[j][ql] * __expf(red_m[j][ql] - M);
    const float scale = __expf(m_w - M) / T;   // 0 if this wave's range all-masked

    // ---- write attn (f32) + P (f16 LDS) + bucket atomics ----
    const size_t arow = ((size_t)z*SS + q0 + ql)*SS;
#pragma unroll
    for (int pt = 0; pt < 8; ++pt) {
        const int k0 = (pt >> 1)*128 + w*32 + (pt & 1)*16 + g*4;
        float pv0 = acc[pt][0]*scale, pv1 = acc[pt][1]*scale;
        float pv2 = acc[pt][2]*scale, pv3 = acc[pt][3]*scale;
        *(float4*)&attn[arow + k0] = make_float4(pv0, pv1, pv2, pv3);
        f16x4 ph; ph[0]=(f16)pv0; ph[1]=(f16)pv1; ph[2]=(f16)pv2; ph[3]=(f16)pv3;
        *(f16x4*)(Pb + swz1024(ql, k0*2)) = ph;
        atomicAdd(&w_s[ql][(avw[pt]      ) & 63], pv0);
        atomicAdd(&w_s[ql][(avw[pt] >>  8) & 63], pv1);
        atomicAdd(&w_s[ql][(avw[pt] >> 16) & 63], pv2);
        atomicAdd(&w_s[ql][(avw[pt] >> 24) & 63], pv3);
    }
    __syncthreads();                           // Pb + w_s complete

    // w -> P2 (f16)
    for (int i = tid; i < 1024; i += 256) {
        const int qq = i >> 6, r = i & 63;
        *(f16*)(P2b + swz128(qq, r*2)) = (f16)w_s[qq][r];
    }

    // ---- PV: ctx[q][d] = P @ V  (wave owns d-cols w*16..w*16+15) ----
    f32x4 acc2 = (f32x4){0.f,0.f,0.f,0.f};
    for (int p = 0; p < 4; ++p) {
        f16x8 vv[4];
        {
            const int r = tid >> 2, cb = (tid & 3) * 32;
            const f16* src = &vth[((size_t)z*DD + r)*SS + p*128 + cb];
#pragma unroll
            for (int u = 0; u < 4; ++u) vv[u] = *(const f16x8*)(src + u*8);
        }
        __syncthreads();                      // prior readers of KVb done (also covers P2b writes)
        {
            const int r = tid >> 2, cb = (tid & 3) * 32;
#pragma unroll
            for (int u = 0; u < 4; ++u)
                *(f16x8*)(KVb + swz256(r, (cb + u*8)*2)) = vv[u];
        }
        __syncthreads();
#pragma unroll
        for (int ks = 0; ks < 4; ++ks) {
            const f16x8 fa = *(const f16x8*)(Pb + swz1024(ql, (p*128 + ks*32 + g*8)*2));
            const f16x8 fb = *(const f16x8*)(KVb + swz256(w*16 + ql, (ks*32 + g*8)*2));
            acc2 = __builtin_amdgcn_mfma_f32_16x16x32_f16(fa, fb, acc2, 0,0,0);
        }
    }
    // + w @ emb_v  (B-frags straight from global evt, 8KB L2-hot)
#pragma unroll
    for (int ks = 0; ks < 2; ++ks) {
        const f16x8 fa = *(const f16x8*)(P2b + swz128(ql, (ks*32 + g*8)*2));
        const f16x8 fb = *(const f16x8*)&evt[(size_t)(w*16 + ql)*RR + ks*32 + g*8];
        acc2 = __builtin_amdgcn_mfma_f32_16x16x32_f16(fa, fb, acc2, 0,0,0);
    }
#pragma unroll
    for (int e = 0; e < 4; ++e)
        ctxh[((size_t)(b*SS) + q0 + g*4 + e)*OO + h*DD + w*16 + ql] = (f16)acc2[e];
}

// ---------------------------------------------------------------------------
// out = ctx(2048x512 f16) @ Wo + bo   (f16 MFMA, WoT pre-transposed)
// ---------------------------------------------------------------------------
__global__ __launch_bounds__(256) void k_out(
    const f16* __restrict__ ctxh, const f16* __restrict__ WoT,
    const float* __restrict__ bo, float* __restrict__ out)
{
    const int n0 = blockIdx.x * 64;
    const int m0 = blockIdx.y * 64;
    __shared__ char Ab[64*128];
    __shared__ char Bb[64*128];
    const int tid = threadIdx.x;
    const int wid = tid >> 6, l = tid & 63;
    const int wr = wid >> 1, wc = wid & 1;
    const int lr = l & 15, lg = l >> 4;
    const int sr = tid >> 2, sc = (tid & 3) * 16;

    f32x4 acc[2][2];
#pragma unroll
    for (int mi = 0; mi < 2; ++mi)
#pragma unroll
        for (int ni = 0; ni < 2; ++ni) acc[mi][ni] = (f32x4){0.f,0.f,0.f,0.f};

    for (int k0 = 0; k0 < 512; k0 += 64) {
        const f16x8 a0 = *(const f16x8*)&ctxh[(size_t)(m0 + sr)*512 + k0 + sc];
        const f16x8 a1 = *(const f16x8*)&ctxh[(size_t)(m0 + sr)*512 + k0 + sc + 8];
        const f16x8 b0 = *(const f16x8*)&WoT[(size_t)(n0 + sr)*512 + k0 + sc];
        const f16x8 b1 = *(const f16x8*)&WoT[(size_t)(n0 + sr)*512 + k0 + sc + 8];
        __syncthreads();
        *(f16x8*)(Ab + swz128(sr, sc*2))    = a0;
        *(f16x8*)(Ab + swz128(sr, sc*2+16)) = a1;
        *(f16x8*)(Bb + swz128(sr, sc*2))    = b0;
        *(f16x8*)(Bb + swz128(sr, sc*2+16)) = b1;
        __syncthreads();
        f16x8 fa[2][2], fb[2][2];
#pragma unroll
        for (int mi = 0; mi < 2; ++mi) {
            const int row = wr*32 + mi*16 + lr;
#pragma unroll
            for (int ks = 0; ks < 2; ++ks)
                fa[mi][ks] = *(const f16x8*)(Ab + swz128(row, ks*64 + lg*16));
        }
#pragma unroll
        for (int ni = 0; ni < 2; ++ni) {
            const int row = wc*32 + ni*16 + lr;
#pragma unroll
            for (int ks = 0; ks < 2; ++ks)
                fb[ni][ks] = *(const f16x8*)(Bb + swz128(row, ks*64 + lg*16));
        }
#pragma unroll
        for (int ks = 0; ks < 2; ++ks)
#pragma unroll
            for (int mi = 0; mi < 2; ++mi)
#pragma unroll
                for (int ni = 0; ni < 2; ++ni)
                    acc[mi][ni] = __builtin_amdgcn_mfma_f32_16x16x32_f16(
                        fa[mi][ks], fb[ni][ks], acc[mi][ni], 0, 0, 0);
    }

#pragma unroll
    for (int ni = 0; ni < 2; ++ni) {
        const int n = n0 + wc*32 + ni*16 + lr;
        const float bv_ = bo[n];
#pragma unroll
        for (int mi = 0; mi < 2; ++mi)
#pragma unroll
            for (int e = 0; e < 4; ++e) {
                const int m = m0 + wr*32 + mi*16 + lg*4 + e;
                out[(size_t)m*512 + n] = acc[mi][ni][e] + bv_;
            }
    }
}

extern "C" void kernel_launch(void* const* d_in, const int* in_sizes, int n_in,
                              void* d_out, int out_size, void* d_ws, size_t ws_size,
                              hipStream_t stream)
{
    const float* key   = (const float*)d_in[0];
    const float* value = (const float*)d_in[1];
    const float* query = (const float*)d_in[2];
    const void*  mask  = d_in[3];
    const int*   adj   = (const int*)d_in[4];
    const float* Wq    = (const float*)d_in[5];
    const float* bq    = (const float*)d_in[6];
    const float* Wk    = (const float*)d_in[7];
    const float* bk    = (const float*)d_in[8];
    const float* Wv    = (const float*)d_in[9];
    const float* bv    = (const float*)d_in[10];
    const float* Wo    = (const float*)d_in[11];
    const float* bo    = (const float*)d_in[12];
    const float* emb_k = (const float*)d_in[13];
    const float* emb_v = (const float*)d_in[14];

    char* w8 = (char*)d_ws;
    f16*   qh   = (f16*)(w8 + WS_QH);
    f16*   kh   = (f16*)(w8 + WS_KH);
    f16*   vth  = (f16*)(w8 + WS_VTH);
    f16*   ctxh = (f16*)(w8 + WS_CTXH);
    float* qe   = (float*)(w8 + WS_QE);
    f16*   WT   = (f16*)(w8 + WS_WT);
    f16*   WoT  = WT + (size_t)3 * 262144;
    f16*   evt  = (f16*)(w8 + WS_EVT);
    int*   flags = (int*)(w8 + WS_FLAGS);

    float* outp = (float*)d_out;                   // (B,S,OUT)
    float* attn = outp + (size_t)BB*SS*OO;         // (B,H,S,S)

    k_detect<<<1, 256, 0, stream>>>(adj, (const unsigned int*)mask, flags);
    k_prep  <<<dim3(8, 8, 5), 256, 0, stream>>>(Wq, Wk, Wv, Wo, emb_v, WT, evt);
    k_proj  <<<dim3(8, 32, 3), 256, 0, stream>>>(query, key, value, WT,
                                                 bq, bk, bv, qh, kh, vth);
    k_qe    <<<1024, 256, 0, stream>>>(qh, emb_k, qe);
    k_attn  <<<dim3(32, 32), 256, 0, stream>>>(qh, kh, vth, qe, adj, mask, flags,
                                               evt, attn, ctxh);
    k_out   <<<dim3(8, 32), 256, 0, stream>>>(ctxh, WoT, bo, outp);
}

// Round 4
// 186.419 us; speedup vs baseline: 2.3512x; 1.1346x over previous
//
#include <hip/hip_runtime.h>
#include <hip/hip_bf16.h>
#include <math.h>

#define BB 4
#define SS 512
#define HH 8
#define DD 64
#define RR 64
#define OO 512

typedef _Float16 f16;
typedef __attribute__((ext_vector_type(8))) _Float16 f16x8;
typedef __attribute__((ext_vector_type(4))) _Float16 f16x4;
typedef __attribute__((ext_vector_type(4))) float f32x4;

// ws byte offsets
#define WS_QH    0u            // 2MB f16 q  [b,h,s,d]
#define WS_KH    (2u<<20)      // 2MB f16 k  [b,h,s,d]
#define WS_VTH   (4u<<20)      // 2MB f16 v^T [b,h,d,s]
#define WS_CTXH  (6u<<20)      // 2MB f16 ctx [b,s,h*d]
#define WS_ADJ8  (8u<<20)      // 1MB u8 packed adj|mask<<7
#define WS_WT    (12u<<20)     // 4 x 512KB f16 transposed weights
#define WS_EVT   (14u<<20)     // 8KB f16 emb_v^T

// XOR swizzle (T2/G4): spread same-16B-column rows across 8 bank slots
__device__ __forceinline__ int swz128(int row, int b)  { return row*128  + (b ^ ((row&7)<<4)); }
__device__ __forceinline__ int swz1024(int row, int b) { return row*1024 + (b ^ ((row&7)<<4)); }

__device__ __forceinline__ void pack8(const float4& x, const float4& y, f16x8& o) {
    o[0]=(f16)x.x; o[1]=(f16)x.y; o[2]=(f16)x.z; o[3]=(f16)x.w;
    o[4]=(f16)y.x; o[5]=(f16)y.y; o[6]=(f16)y.z; o[7]=(f16)y.w;
}

// ---------------------------------------------------------------------------
// Pack adj+mask -> u8 (adj&63 | mask<<7). Per-block inline dtype detection
// (int64 adj: odd words all zero; byte mask: words > 1). 1024 blocks.
// ---------------------------------------------------------------------------
__global__ __launch_bounds__(256) void k_pack(const int* __restrict__ adj,
                                              const void* __restrict__ mask,
                                              unsigned char* __restrict__ adj8)
{
    const int tid = threadIdx.x;
    __shared__ int s_odd, s_big;
    if (tid == 0) { s_odd = 0; s_big = 0; }
    __syncthreads();
    int odd = 0, big = 0;
    const unsigned int* mu = (const unsigned int*)mask;
    for (int i = tid; i < 512; i += 256) {
        odd |= (adj[2*i + 1] != 0);
        big |= (mu[i] > 1u);
    }
    if (odd) atomicOr(&s_odd, 1);
    if (big) atomicOr(&s_big, 1);
    __syncthreads();
    const int f64 = s_odd ? 0 : 1;
    const int fbyte = s_big;

    const int t = blockIdx.x * 256 + tid;          // output u32 index
    const int e0 = t * 4;
    const int b = e0 >> 18, k0 = e0 & 511;
    int a[4];
    if (f64) {
        const int4 A = ((const int4*)adj)[2*t];
        const int4 Bv = ((const int4*)adj)[2*t + 1];
        a[0] = A.x; a[1] = A.z; a[2] = Bv.x; a[3] = Bv.z;
    } else {
        const int4 A = ((const int4*)adj)[t];
        a[0] = A.x; a[1] = A.y; a[2] = A.z; a[3] = A.w;
    }
    unsigned int mbits;
    if (fbyte) {
        const unsigned int mw = *(const unsigned int*)((const unsigned char*)mask + b*512 + k0);
        mbits = ((mw & 255u) ? 1u : 0) | (((mw >> 8) & 255u) ? 2u : 0)
              | (((mw >> 16) & 255u) ? 4u : 0) | (((mw >> 24) & 255u) ? 8u : 0);
    } else {
        const int4 mv = ((const int4*)mask)[(b*512 + k0) >> 2];
        mbits = (mv.x ? 1u : 0) | (mv.y ? 2u : 0) | (mv.z ? 4u : 0) | (mv.w ? 8u : 0);
    }
    unsigned int w = 0;
#pragma unroll
    for (int j = 0; j < 4; ++j)
        w |= ((unsigned)(a[j] & 63) | (((mbits >> j) & 1u) << 7)) << (8*j);
    ((unsigned int*)adj8)[t] = w;
}

// ---------------------------------------------------------------------------
// Prep: transpose weights to f16  WT[z][n][k] = W[k][n]; evt[d][r] = emb_v[r][d]
// ---------------------------------------------------------------------------
__global__ __launch_bounds__(256) void k_prep(
    const float* __restrict__ Wq, const float* __restrict__ Wk,
    const float* __restrict__ Wv, const float* __restrict__ Wo,
    const float* __restrict__ emb_v, f16* __restrict__ WT, f16* __restrict__ evt)
{
    const int z = blockIdx.z;
    __shared__ float tile[64][65];
    const int tid = threadIdx.x;
    const int r = tid >> 2, c4 = (tid & 3) * 16;
    if (z < 4) {
        const float* W = (z==0)?Wq:(z==1)?Wk:(z==2)?Wv:Wo;
        f16* T = WT + (size_t)z * 262144;
        const int k0 = blockIdx.y * 64, n0 = blockIdx.x * 64;
#pragma unroll
        for (int u = 0; u < 4; ++u) {
            const float4 w4 = *(const float4*)&W[(size_t)(k0 + r)*512 + n0 + c4 + u*4];
            tile[r][c4+u*4+0] = w4.x; tile[r][c4+u*4+1] = w4.y;
            tile[r][c4+u*4+2] = w4.z; tile[r][c4+u*4+3] = w4.w;
        }
        __syncthreads();
        f16x8 v0, v1;
#pragma unroll
        for (int j = 0; j < 8; ++j) { v0[j] = (f16)tile[c4+j][r]; v1[j] = (f16)tile[c4+8+j][r]; }
        f16* dst = &T[(size_t)(n0 + r)*512 + k0 + c4];
        *(f16x8*)dst = v0; *(f16x8*)(dst + 8) = v1;
    } else {
        if (blockIdx.x | blockIdx.y) return;
#pragma unroll
        for (int u = 0; u < 4; ++u) {
            const float4 w4 = *(const float4*)&emb_v[(size_t)r*64 + c4 + u*4];
            tile[r][c4+u*4+0] = w4.x; tile[r][c4+u*4+1] = w4.y;
            tile[r][c4+u*4+2] = w4.z; tile[r][c4+u*4+3] = w4.w;
        }
        __syncthreads();
        f16x8 v0, v1;
#pragma unroll
        for (int j = 0; j < 8; ++j) { v0[j] = (f16)tile[c4+j][r]; v1[j] = (f16)tile[c4+8+j][r]; }
        f16* dst = &evt[(size_t)r*64 + c4];
        *(f16x8*)dst = v0; *(f16x8*)(dst + 8) = v1;
    }
}

// ---------------------------------------------------------------------------
// QKV projection, f16 MFMA, double-buffered LDS, 1 barrier/iter.
// ---------------------------------------------------------------------------
__global__ __launch_bounds__(256) void k_proj(
    const float* __restrict__ query, const float* __restrict__ key, const float* __restrict__ value,
    const f16* __restrict__ WT,
    const float* __restrict__ bq, const float* __restrict__ bk, const float* __restrict__ bv,
    f16* __restrict__ qh, f16* __restrict__ kh, f16* __restrict__ vth)
{
    const int z = blockIdx.z;
    const float* A    = (z == 0) ? query : (z == 1) ? key : value;
    const f16*   Bt   = WT + (size_t)z * 262144;
    const float* bias = (z == 0) ? bq : (z == 1) ? bk : bv;

    const int n0 = blockIdx.x * 64;
    const int m0 = blockIdx.y * 64;
    __shared__ char Ab[2][8192];
    __shared__ char Bb[2][8192];
    const int tid = threadIdx.x;
    const int wid = tid >> 6, l = tid & 63;
    const int wr = wid >> 1, wc = wid & 1;
    const int lr = l & 15, lg = l >> 4;
    const int sr = tid >> 2, sc = (tid & 3) * 16;

    const float* Ap = &A[(size_t)(m0 + sr)*512 + sc];
    const f16*   Bp = &Bt[(size_t)(n0 + sr)*512 + sc];

    f32x4 acc[2][2];
#pragma unroll
    for (int mi = 0; mi < 2; ++mi)
#pragma unroll
        for (int ni = 0; ni < 2; ++ni) acc[mi][ni] = (f32x4){0.f,0.f,0.f,0.f};

    float4 a4[4]; f16x8 b0, b1;
#pragma unroll
    for (int u = 0; u < 4; ++u) a4[u] = *(const float4*)(Ap + u*4);
    b0 = *(const f16x8*)Bp; b1 = *(const f16x8*)(Bp + 8);
    {
        f16x8 p0, p1;
        pack8(a4[0], a4[1], p0); pack8(a4[2], a4[3], p1);
        *(f16x8*)(Ab[0] + swz128(sr, sc*2))    = p0;
        *(f16x8*)(Ab[0] + swz128(sr, sc*2+16)) = p1;
        *(f16x8*)(Bb[0] + swz128(sr, sc*2))    = b0;
        *(f16x8*)(Bb[0] + swz128(sr, sc*2+16)) = b1;
    }
#pragma unroll
    for (int t = 0; t < 8; ++t) {
        __syncthreads();
        if (t < 7) {
#pragma unroll
            for (int u = 0; u < 4; ++u) a4[u] = *(const float4*)(Ap + (t+1)*64 + u*4);
            b0 = *(const f16x8*)(Bp + (t+1)*64);
            b1 = *(const f16x8*)(Bp + (t+1)*64 + 8);
        }
        const char* Ac = Ab[t & 1];
        const char* Bc = Bb[t & 1];
        f16x8 fa[2][2], fb[2][2];
#pragma unroll
        for (int mi = 0; mi < 2; ++mi) {
            const int row = wr*32 + mi*16 + lr;
#pragma unroll
            for (int ks = 0; ks < 2; ++ks)
                fa[mi][ks] = *(const f16x8*)(Ac + swz128(row, ks*64 + lg*16));
        }
#pragma unroll
        for (int ni = 0; ni < 2; ++ni) {
            const int row = wc*32 + ni*16 + lr;
#pragma unroll
            for (int ks = 0; ks < 2; ++ks)
                fb[ni][ks] = *(const f16x8*)(Bc + swz128(row, ks*64 + lg*16));
        }
#pragma unroll
        for (int ks = 0; ks < 2; ++ks)
#pragma unroll
            for (int mi = 0; mi < 2; ++mi)
#pragma unroll
                for (int ni = 0; ni < 2; ++ni)
                    acc[mi][ni] = __builtin_amdgcn_mfma_f32_16x16x32_f16(
                        fa[mi][ks], fb[ni][ks], acc[mi][ni], 0, 0, 0);
        if (t < 7) {
            f16x8 p0, p1;
            pack8(a4[0], a4[1], p0); pack8(a4[2], a4[3], p1);
            char* An = Ab[(t+1) & 1];
            char* Bn = Bb[(t+1) & 1];
            *(f16x8*)(An + swz128(sr, sc*2))    = p0;
            *(f16x8*)(An + swz128(sr, sc*2+16)) = p1;
            *(f16x8*)(Bn + swz128(sr, sc*2))    = b0;
            *(f16x8*)(Bn + swz128(sr, sc*2+16)) = b1;
        }
    }

#pragma unroll
    for (int ni = 0; ni < 2; ++ni) {
        const int n = n0 + wc*32 + ni*16 + lr;
        const float bv_ = bias[n];
        const int h = n >> 6, d = n & 63;
#pragma unroll
        for (int mi = 0; mi < 2; ++mi)
#pragma unroll
            for (int e = 0; e < 4; ++e) {
                const int m = m0 + wr*32 + mi*16 + lg*4 + e;
                const int b = m >> 9, s = m & 511;
                const f16 v = (f16)(acc[mi][ni][e] + bv_);
                if (z == 2)       vth[((size_t)(b*HH + h)*DD + d)*SS + s] = v;
                else if (z == 1)  kh [((size_t)(b*HH + h)*SS + s)*DD + d] = v;
                else              qh [((size_t)(b*HH + h)*SS + s)*DD + d] = v;
            }
    }
}

// ---------------------------------------------------------------------------
// Fully fused attention. 4 waves, 16 q-rows x one (b,h). qe via MFMA in-block;
// K/V streamed in 64-row panels, double-buffered (1 barrier/panel); adj+mask
// from packed u8 (register-prefetched at kernel top); QE/w-bucket LDS union.
// ---------------------------------------------------------------------------
__global__ __launch_bounds__(256, 4) void k_attn(
    const f16* __restrict__ qh, const f16* __restrict__ kh, const f16* __restrict__ vth,
    const unsigned char* __restrict__ adj8, const float* __restrict__ emb_k,
    const f16* __restrict__ evt, float* __restrict__ attn, f16* __restrict__ ctxh)
{
    // bijective XCD swizzle: 1024 blocks -> 128 consecutive per XCD
    const int wg = (blockIdx.x & 7) * 128 + (blockIdx.x >> 3);
    const int z = wg >> 5, qb = wg & 31;
    const int b = z >> 3, h = z & 7;
    const int q0 = qb * 16;
    const int tid = threadIdx.x, w = tid >> 6, l = tid & 63;
    const int lr = l & 15, lg = l >> 4;
    const int sr = tid >> 2, sce = (tid & 3) * 16;

    __shared__ char KV[2][8192];     // K/V panels [64][64] f16, swz128
    __shared__ char Qb_[2048];       // Q [16][64] f16, swz128
    __shared__ char Pb[16384];       // P [16][512] f16, swz1024
    __shared__ float QW[16][65];     // qe table, then (after zero) bucket acc
    __shared__ float red_m[4][16], red_s[4][16];

    // ---- P0: issue all independent loads ----
    unsigned int avw[8];
    const unsigned char* arow = &adj8[((size_t)b*SS + q0 + lr)*SS];
#pragma unroll
    for (int p = 0; p < 8; ++p)
        avw[p] = *(const unsigned int*)(arow + p*64 + w*16 + lg*4);
    f32x4 e4[4];
    {
        const float* ep = &emb_k[(size_t)(w*16 + lr)*DD];
        e4[0] = *(const f32x4*)(ep + lg*8);
        e4[1] = *(const f32x4*)(ep + lg*8 + 4);
        e4[2] = *(const f32x4*)(ep + 32 + lg*8);
        e4[3] = *(const f32x4*)(ep + 32 + lg*8 + 4);
    }
    f16x8 st0 = *(const f16x8*)&kh[((size_t)z*SS + sr)*DD + sce];
    f16x8 st1 = *(const f16x8*)&kh[((size_t)z*SS + sr)*DD + sce + 8];
    if (tid < 64) {
        const int r = tid >> 2, ce = (tid & 3) * 16;
        const f16* src = &qh[((size_t)z*SS + q0 + r)*DD + ce];
        *(f16x8*)(Qb_ + swz128(r, ce*2))      = *(const f16x8*)src;
        *(f16x8*)(Qb_ + swz128(r, ce*2 + 16)) = *(const f16x8*)(src + 8);
    }
    __syncthreads();

    // ---- P1: qe via MFMA (wave w owns r-tile w); stage K panel 0 ----
    const f16x8 fb0 = *(const f16x8*)(Qb_ + swz128(lr, lg*16));
    const f16x8 fb1 = *(const f16x8*)(Qb_ + swz128(lr, 64 + lg*16));
    {
        f16x8 fe0, fe1;
#pragma unroll
        for (int j = 0; j < 4; ++j) {
            fe0[j] = (f16)e4[0][j]; fe0[4+j] = (f16)e4[1][j];
            fe1[j] = (f16)e4[2][j]; fe1[4+j] = (f16)e4[3][j];
        }
        f32x4 aq = (f32x4){0.f,0.f,0.f,0.f};
        aq = __builtin_amdgcn_mfma_f32_16x16x32_f16(fe0, fb0, aq, 0, 0, 0);
        aq = __builtin_amdgcn_mfma_f32_16x16x32_f16(fe1, fb1, aq, 0, 0, 0);
#pragma unroll
        for (int e = 0; e < 4; ++e) QW[lr][w*16 + lg*4 + e] = aq[e];
    }
    *(f16x8*)(KV[0] + swz128(sr, sce*2))      = st0;
    *(f16x8*)(KV[0] + swz128(sr, sce*2 + 16)) = st1;
    __syncthreads();

    // ---- P2: QK^T, 8 panels of 64 k, double-buffered ----
    f32x4 acc[8];
#pragma unroll
    for (int p = 0; p < 8; ++p) acc[p] = (f32x4){0.f,0.f,0.f,0.f};
#pragma unroll
    for (int p = 0; p < 8; ++p) {
        if (p < 7) {
            st0 = *(const f16x8*)&kh[((size_t)z*SS + (p+1)*64 + sr)*DD + sce];
            st1 = *(const f16x8*)&kh[((size_t)z*SS + (p+1)*64 + sr)*DD + sce + 8];
        }
        const char* Kc = KV[p & 1];
        const f16x8 fa0 = *(const f16x8*)(Kc + swz128(w*16 + lr, lg*16));
        const f16x8 fa1 = *(const f16x8*)(Kc + swz128(w*16 + lr, 64 + lg*16));
        acc[p] = __builtin_amdgcn_mfma_f32_16x16x32_f16(fa0, fb0, acc[p], 0, 0, 0);
        acc[p] = __builtin_amdgcn_mfma_f32_16x16x32_f16(fa1, fb1, acc[p], 0, 0, 0);
        if (p < 7) {
            char* Kn = KV[(p+1) & 1];
            *(f16x8*)(Kn + swz128(sr, sce*2))      = st0;
            *(f16x8*)(Kn + swz128(sr, sce*2 + 16)) = st1;
            __syncthreads();
        }
    }

    // ---- P3: bias gather + mask + softmax ----
    float mx = -1e30f;
#pragma unroll
    for (int p = 0; p < 8; ++p)
#pragma unroll
        for (int e = 0; e < 4; ++e) {
            const unsigned a = (avw[p] >> (8*e)) & 255u;
            float s = (acc[p][e] + QW[lr][a & 63]) * 0.125f;
            s = (a & 128u) ? -1e30f : s;
            acc[p][e] = s;
            mx = fmaxf(mx, s);
        }
    mx = fmaxf(mx, __shfl_xor(mx, 16, 64));
    mx = fmaxf(mx, __shfl_xor(mx, 32, 64));
    float sm = 0.f;
#pragma unroll
    for (int p = 0; p < 8; ++p)
#pragma unroll
        for (int e = 0; e < 4; ++e) {
            const float ev = __expf(acc[p][e] - mx);
            acc[p][e] = ev; sm += ev;
        }
    sm += __shfl_xor(sm, 16, 64);
    sm += __shfl_xor(sm, 32, 64);
    if (l < 16) { red_m[w][lr] = mx; red_s[w][lr] = sm; }
    __syncthreads();
    float M = red_m[0][lr];
#pragma unroll
    for (int j = 1; j < 4; ++j) M = fmaxf(M, red_m[j][lr]);
    float T = 0.f;
#pragma unroll
    for (int j = 0; j < 4; ++j) T += red_s[j][lr] * __expf(red_m[j][lr] - M);
    const float scale = __expf(mx - M) / T;

    // stage V panel 0 (issue loads before zero-phase to hide latency)
    f16x8 v0 = *(const f16x8*)&vth[((size_t)z*DD + sr)*SS + sce];
    f16x8 v1 = *(const f16x8*)&vth[((size_t)z*DD + sr)*SS + sce + 8];

    // zero bucket accumulator (QW reuse: all qe reads completed before barrier)
    for (int i = tid; i < 16*65; i += 256) (&QW[0][0])[i] = 0.f;
    __syncthreads();

    // ---- P4: attn write + P (f16 LDS) + bucket atomics + V panel 0 ----
#pragma unroll
    for (int p = 0; p < 8; ++p) {
        const float pv0 = acc[p][0]*scale, pv1 = acc[p][1]*scale;
        const float pv2 = acc[p][2]*scale, pv3 = acc[p][3]*scale;
        *(float4*)&attn[((size_t)z*SS + q0 + lr)*SS + p*64 + w*16 + lg*4] =
            make_float4(pv0, pv1, pv2, pv3);
        f16x4 ph; ph[0]=(f16)pv0; ph[1]=(f16)pv1; ph[2]=(f16)pv2; ph[3]=(f16)pv3;
        *(f16x4*)(Pb + swz1024(lr, (p*64 + w*16 + lg*4)*2)) = ph;
        atomicAdd(&QW[lr][(avw[p]      ) & 63], pv0);
        atomicAdd(&QW[lr][(avw[p] >>  8) & 63], pv1);
        atomicAdd(&QW[lr][(avw[p] >> 16) & 63], pv2);
        atomicAdd(&QW[lr][(avw[p] >> 24) & 63], pv3);
    }
    *(f16x8*)(KV[0] + swz128(sr, sce*2))      = v0;
    *(f16x8*)(KV[0] + swz128(sr, sce*2 + 16)) = v1;
    __syncthreads();

    // ---- P5: PV, 8 panels double-buffered; + w @ emb_v ----
    f32x4 acc2 = (f32x4){0.f,0.f,0.f,0.f};
#pragma unroll
    for (int p = 0; p < 8; ++p) {
        if (p < 7) {
            v0 = *(const f16x8*)&vth[((size_t)z*DD + sr)*SS + (p+1)*64 + sce];
            v1 = *(const f16x8*)&vth[((size_t)z*DD + sr)*SS + (p+1)*64 + sce + 8];
        }
        const char* Vc = KV[p & 1];
#pragma unroll
        for (int ks = 0; ks < 2; ++ks) {
            const f16x8 fa = *(const f16x8*)(Pb + swz1024(lr, p*128 + ks*64 + lg*16));
            const f16x8 fb = *(const f16x8*)(Vc + swz128(w*16 + lr, ks*64 + lg*16));
            acc2 = __builtin_amdgcn_mfma_f32_16x16x32_f16(fa, fb, acc2, 0, 0, 0);
        }
        if (p < 7) {
            char* Vn = KV[(p+1) & 1];
            *(f16x8*)(Vn + swz128(sr, sce*2))      = v0;
            *(f16x8*)(Vn + swz128(sr, sce*2 + 16)) = v1;
            __syncthreads();
        }
    }
#pragma unroll
    for (int ks = 0; ks < 2; ++ks) {
        f16x8 fa;
        const float* wp = &QW[lr][ks*32 + lg*8];
#pragma unroll
        for (int j = 0; j < 8; ++j) fa[j] = (f16)wp[j];
        const f16x8 fb = *(const f16x8*)&evt[(size_t)(w*16 + lr)*RR + ks*32 + lg*8];
        acc2 = __builtin_amdgcn_mfma_f32_16x16x32_f16(fa, fb, acc2, 0, 0, 0);
    }
#pragma unroll
    for (int e = 0; e < 4; ++e)
        ctxh[((size_t)b*SS + q0 + lg*4 + e)*OO + h*DD + w*16 + lr] = (f16)acc2[e];
}

// ---------------------------------------------------------------------------
// out = ctx(2048x512 f16) @ Wo + bo, double-buffered f16 MFMA.
// ---------------------------------------------------------------------------
__global__ __launch_bounds__(256) void k_out(
    const f16* __restrict__ ctxh, const f16* __restrict__ WoT,
    const float* __restrict__ bo, float* __restrict__ out)
{
    const int n0 = blockIdx.x * 64;
    const int m0 = blockIdx.y * 64;
    __shared__ char Ab[2][8192];
    __shared__ char Bb[2][8192];
    const int tid = threadIdx.x;
    const int wid = tid >> 6, l = tid & 63;
    const int wr = wid >> 1, wc = wid & 1;
    const int lr = l & 15, lg = l >> 4;
    const int sr = tid >> 2, sc = (tid & 3) * 16;

    const f16* Ap = &ctxh[(size_t)(m0 + sr)*512 + sc];
    const f16* Bp = &WoT[(size_t)(n0 + sr)*512 + sc];

    f32x4 acc[2][2];
#pragma unroll
    for (int mi = 0; mi < 2; ++mi)
#pragma unroll
        for (int ni = 0; ni < 2; ++ni) acc[mi][ni] = (f32x4){0.f,0.f,0.f,0.f};

    f16x8 a0 = *(const f16x8*)Ap, a1 = *(const f16x8*)(Ap + 8);
    f16x8 b0 = *(const f16x8*)Bp, b1 = *(const f16x8*)(Bp + 8);
    *(f16x8*)(Ab[0] + swz128(sr, sc*2))    = a0;
    *(f16x8*)(Ab[0] + swz128(sr, sc*2+16)) = a1;
    *(f16x8*)(Bb[0] + swz128(sr, sc*2))    = b0;
    *(f16x8*)(Bb[0] + swz128(sr, sc*2+16)) = b1;
#pragma unroll
    for (int t = 0; t < 8; ++t) {
        __syncthreads();
        if (t < 7) {
            a0 = *(const f16x8*)(Ap + (t+1)*64); a1 = *(const f16x8*)(Ap + (t+1)*64 + 8);
            b0 = *(const f16x8*)(Bp + (t+1)*64); b1 = *(const f16x8*)(Bp + (t+1)*64 + 8);
        }
        const char* Ac = Ab[t & 1];
        const char* Bc = Bb[t & 1];
        f16x8 fa[2][2], fb[2][2];
#pragma unroll
        for (int mi = 0; mi < 2; ++mi) {
            const int row = wr*32 + mi*16 + lr;
#pragma unroll
            for (int ks = 0; ks < 2; ++ks)
                fa[mi][ks] = *(const f16x8*)(Ac + swz128(row, ks*64 + lg*16));
        }
#pragma unroll
        for (int ni = 0; ni < 2; ++ni) {
            const int row = wc*32 + ni*16 + lr;
#pragma unroll
            for (int ks = 0; ks < 2; ++ks)
                fb[ni][ks] = *(const f16x8*)(Bc + swz128(row, ks*64 + lg*16));
        }
#pragma unroll
        for (int ks = 0; ks < 2; ++ks)
#pragma unroll
            for (int mi = 0; mi < 2; ++mi)
#pragma unroll
                for (int ni = 0; ni < 2; ++ni)
                    acc[mi][ni] = __builtin_amdgcn_mfma_f32_16x16x32_f16(
                        fa[mi][ks], fb[ni][ks], acc[mi][ni], 0, 0, 0);
        if (t < 7) {
            char* An = Ab[(t+1) & 1];
            char* Bn = Bb[(t+1) & 1];
            *(f16x8*)(An + swz128(sr, sc*2))    = a0;
            *(f16x8*)(An + swz128(sr, sc*2+16)) = a1;
            *(f16x8*)(Bn + swz128(sr, sc*2))    = b0;
            *(f16x8*)(Bn + swz128(sr, sc*2+16)) = b1;
        }
    }

#pragma unroll
    for (int ni = 0; ni < 2; ++ni) {
        const int n = n0 + wc*32 + ni*16 + lr;
        const float bv_ = bo[n];
#pragma unroll
        for (int mi = 0; mi < 2; ++mi)
#pragma unroll
            for (int e = 0; e < 4; ++e) {
                const int m = m0 + wr*32 + mi*16 + lg*4 + e;
                out[(size_t)m*512 + n] = acc[mi][ni][e] + bv_;
            }
    }
}

extern "C" void kernel_launch(void* const* d_in, const int* in_sizes, int n_in,
                              void* d_out, int out_size, void* d_ws, size_t ws_size,
                              hipStream_t stream)
{
    const float* key   = (const float*)d_in[0];
    const float* value = (const float*)d_in[1];
    const float* query = (const float*)d_in[2];
    const void*  mask  = d_in[3];
    const int*   adj   = (const int*)d_in[4];
    const float* Wq    = (const float*)d_in[5];
    const float* bq    = (const float*)d_in[6];
    const float* Wk    = (const float*)d_in[7];
    const float* bk    = (const float*)d_in[8];
    const float* Wv    = (const float*)d_in[9];
    const float* bv    = (const float*)d_in[10];
    const float* Wo    = (const float*)d_in[11];
    const float* bo    = (const float*)d_in[12];
    const float* emb_k = (const float*)d_in[13];
    const float* emb_v = (const float*)d_in[14];

    char* w8 = (char*)d_ws;
    f16* qh   = (f16*)(w8 + WS_QH);
    f16* kh   = (f16*)(w8 + WS_KH);
    f16* vth  = (f16*)(w8 + WS_VTH);
    f16* ctxh = (f16*)(w8 + WS_CTXH);
    unsigned char* adj8p = (unsigned char*)(w8 + WS_ADJ8);
    f16* WT   = (f16*)(w8 + WS_WT);
    f16* WoT  = WT + (size_t)3 * 262144;
    f16* evt  = (f16*)(w8 + WS_EVT);

    float* outp = (float*)d_out;                   // (B,S,OUT)
    float* attn = outp + (size_t)BB*SS*OO;         // (B,H,S,S)

    k_pack<<<1024, 256, 0, stream>>>(adj, mask, adj8p);
    k_prep<<<dim3(8, 8, 5), 256, 0, stream>>>(Wq, Wk, Wv, Wo, emb_v, WT, evt);
    k_proj<<<dim3(8, 32, 3), 256, 0, stream>>>(query, key, value, WT,
                                               bq, bk, bv, qh, kh, vth);
    k_attn<<<1024, 256, 0, stream>>>(qh, kh, vth, adj8p, emb_k, evt, attn, ctxh);
    k_out <<<dim3(8, 32), 256, 0, stream>>>(ctxh, WoT, bo, outp);
}